// Round 7
// baseline (2133.616 us; speedup 1.0000x reference)
//
#include <hip/hip_runtime.h>

typedef unsigned short u16;
typedef __bf16 bf16x8 __attribute__((ext_vector_type(8)));
typedef float f32x4 __attribute__((ext_vector_type(4)));

#define T_STEPS 8
#define PLANE 1156            // 34*34 padded spatial positions
#define ROWB 2176             // 34 * 32ch * 2B : bytes per padded row in LDS tile

__device__ __forceinline__ u16 f2bf(float f) {
    unsigned u = __float_as_uint(f);
    return (u16)((u + 0x7fff + ((u >> 16) & 1)) >> 16);
}
__device__ __forceinline__ float sigmoidf(float x) {
    return 1.f / (1.f + expf(-x));
}
// async global->LDS, 16B per lane. LDS dest must be base + lane*16 (linear).
__device__ __forceinline__ void gl_lds16(const void* g, void* l) {
    __builtin_amdgcn_global_load_lds(
        (const __attribute__((address_space(1))) void*)g,
        (__attribute__((address_space(3))) void*)l, 16, 0, 0);
}

// ---------------------------------------------------------------------------
// Repack conv_w (fp32) [2048][1024][3][3] -> bf16 GEMM layouts, K reordered
// ci-chunk-major: kt = cc*9 + r.  Both: [co_blk(16)][kt(144)][quad(4)]
// [co_in(128)][j(8)].
// x rows: co = co_blk*128 + co_in (plain).
// h rows gate-in-reg: co = (co_in&3)*512 + co_blk*32 + (co_in>>2).
// Coalesced: block = (part, co_blk, cc, half); phase 1 reads 144 contiguous
// floats per co row (float4); phase 2 gathers j from LDS, writes 16B chunks.
// ---------------------------------------------------------------------------
__global__ __launch_bounds__(256) void repack_w(const float* __restrict__ w,
                         u16* __restrict__ wx, u16* __restrict__ wh) {
    __shared__ u16 L[128][150];               // 144 used; 150 breaks conflicts
    const int tid = threadIdx.x;
    const int bidx = blockIdx.x;              // 1024 blocks
    const int part   = bidx >> 9;             // 0 = x, 1 = h
    const int co_blk = (bidx >> 5) & 15;
    const int cc     = (bidx >> 1) & 15;
    const int half   = bidx & 1;              // quads 2*half .. 2*half+1
    const int cibase = part * 512 + cc * 32 + half * 16;

#pragma unroll
    for (int k = 0; k < 18; ++k) {
        int i = tid + k * 256;                // 0..4607 (128 rows x 36 float4)
        int co_in = i / 36;
        int p4 = i - co_in * 36;
        int co = part ? ((co_in & 3) * 512 + co_blk * 32 + (co_in >> 2))
                      : (co_blk * 128 + co_in);
        const float4 v = *(const float4*)(w + (size_t)co * 9216
                                            + (size_t)cibase * 9 + p4 * 4);
        L[co_in][p4 * 4 + 0] = f2bf(v.x);
        L[co_in][p4 * 4 + 1] = f2bf(v.y);
        L[co_in][p4 * 4 + 2] = f2bf(v.z);
        L[co_in][p4 * 4 + 3] = f2bf(v.w);
    }
    __syncthreads();
    u16* wout = part ? wh : wx;
#pragma unroll
    for (int k = 0; k < 9; ++k) {
        int v2 = tid + k * 256;               // 0..2303
        int co_in = v2 & 127;
        int rq = v2 >> 7;                     // 0..17
        int q01 = rq >= 9;
        int r = rq - q01 * 9;
        int quad = half * 2 + q01;
        union { u16 u[8]; uint4 q; } tmp;
#pragma unroll
        for (int j = 0; j < 8; ++j)
            tmp.u[j] = L[co_in][(q01 * 8 + j) * 9 + r];
        *(uint4*)(wout + ((((size_t)co_blk * 144 + cc * 9 + r) * 4 + quad) * 128
                          + co_in) * 8) = tmp.q;
    }
}

// ---------------------------------------------------------------------------
// x [2][512][8][32][32] f32 -> Xp [b*8+t][34][34][512] bf16 (interior only;
// border pre-zeroed by memset). Reads coalesced along x.
// ---------------------------------------------------------------------------
__global__ __launch_bounds__(256) void pretransform_x(
    const float* __restrict__ x, u16* __restrict__ Xp) {
    const int bt = blockIdx.x >> 5;            // b*8+t
    const int y  = blockIdx.x & 31;
    const int b  = bt >> 3;
    const int xx = threadIdx.x & 31, cg0 = threadIdx.x >> 5;
    const float* src = x + ((size_t)(b * 512) * T_STEPS + (bt & 7)) * 1024
                         + y * 32 + xx;
    u16* dst = Xp + (((size_t)bt * 34 + y + 1) * 34 + (xx + 1)) * 512;
#pragma unroll
    for (int it = 0; it < 8; ++it) {
        const int cig = cg0 + it * 8;          // 0..63 (8-channel group)
        union { u16 u[8]; uint4 v; } pk;
#pragma unroll
        for (int j = 0; j < 8; ++j)
            pk.u[j] = f2bf(src[(size_t)(cig * 8 + j) * 8192]);
        *(uint4*)(dst + cig * 8) = pk.v;
    }
}

// ---------------------------------------------------------------------------
// Shared GEMM machinery: A global->VGPR 3-deep ring (+2 taps, L2-resident via
// XCD swizzle), B chunk tile in LDS (dbuf per chunk, compile-time base via
// chunk-parity unroll), B fragments in a 3-deep register ring read +2 taps
// ahead (absorbs LDS queueing latency).  One counted vmcnt + s_barrier per
// chunk; never drains prefetches.  vmcnt: cc-head newest = 7 taps x 2
// A-prefetches since B(cc) -> 14; cc==0: prologue B + 2 taps x 2 -> 4.
// No setprio (null/negative for lockstep GEMM, m190).
// ---------------------------------------------------------------------------
#define READB4(dstv, btcp, rr) {                                             \
    const int ry_ = (rr) / 3, rx_ = (rr) % 3;                                \
    dstv[0] = *(const bf16x8*)((btcp) + wnrow + (0 + ry_) * ROWB + colb[0][rx_]); \
    dstv[1] = *(const bf16x8*)((btcp) + wnrow + (0 + ry_) * ROWB + colb[1][rx_]); \
    dstv[2] = *(const bf16x8*)((btcp) + wnrow + (1 + ry_) * ROWB + colb[0][rx_]); \
    dstv[3] = *(const bf16x8*)((btcp) + wnrow + (1 + ry_) * ROWB + colb[1][rx_]); }

#define READB2(dstv, btcp, rr) {                                             \
    const int ry_ = (rr) / 3, rx_ = (rr) % 3;                                \
    dstv[0] = *(const bf16x8*)((btcp) + wnrow + ry_ * ROWB + colb[0][rx_]);  \
    dstv[1] = *(const bf16x8*)((btcp) + wnrow + ry_ * ROWB + colb[1][rx_]); }

#define XCHUNK(ccv, CBV)                                                      \
{                                                                             \
    const int cc_ = (ccv);                                                    \
    const char* btc = (const char*)&Bt[CBV][0];                               \
    asm volatile("" ::: "memory");                                            \
    if (cc_ == 0) asm volatile("s_waitcnt vmcnt(4)" ::: "memory");            \
    else          asm volatile("s_waitcnt vmcnt(14)" ::: "memory");           \
    __builtin_amdgcn_s_barrier();                                             \
    asm volatile("" ::: "memory");                                            \
    READB4(breg[0], btc, 0);                                                  \
    READB4(breg[1], btc, 1);                                                  \
    _Pragma("unroll")                                                         \
    for (int r = 0; r < 9; ++r) {                                             \
        const int kt_ = cc_ * 9 + r;                                          \
        if (cc_ < 15 || r < 7) {                                              \
            _Pragma("unroll")                                                 \
            for (int mt = 0; mt < 2; ++mt)                                    \
                areg[(r + 2) % 3][mt] =                                       \
                    *(const bf16x8*)(Aq + (size_t)(kt_ + 2) * 512 + mt * 16); \
        }                                                                     \
        if (r == 1 && cc_ < 15) {                                             \
            const u16* gs = pbase + (cc_ + 1) * 32;                           \
            gl_lds16(gs + src0, &Bt[(CBV) ^ 1][c0 * 8]);                      \
            if (do1) gl_lds16(gs + src1, &Bt[(CBV) ^ 1][c1 * 8]);             \
        }                                                                     \
        if (r < 7) READB4(breg[(r + 2) % 3], btc, r + 2);                     \
        _Pragma("unroll")                                                     \
        for (int mt = 0; mt < 2; ++mt)                                        \
            _Pragma("unroll")                                                 \
            for (int nt = 0; nt < 4; ++nt)                                    \
                acc[mt][nt] = __builtin_amdgcn_mfma_f32_16x16x32_bf16(        \
                    areg[r % 3][mt], breg[r % 3][nt], acc[mt][nt], 0, 0, 0);  \
    }                                                                         \
}

#define HCHUNK(ccv, CBV)                                                      \
{                                                                             \
    const int cc_ = (ccv);                                                    \
    const char* btc = (const char*)&Bt[CBV][0];                               \
    asm volatile("" ::: "memory");                                            \
    if (cc_ == 0) asm volatile("s_waitcnt vmcnt(4)" ::: "memory");            \
    else          asm volatile("s_waitcnt vmcnt(14)" ::: "memory");           \
    __builtin_amdgcn_s_barrier();                                             \
    asm volatile("" ::: "memory");                                            \
    READB2(breg[0], btc, 0);                                                  \
    READB2(breg[1], btc, 1);                                                  \
    _Pragma("unroll")                                                         \
    for (int r = 0; r < 9; ++r) {                                             \
        const int kt_ = cc_ * 9 + r;                                          \
        if (cc_ < 15 || r < 7) {                                              \
            _Pragma("unroll")                                                 \
            for (int mt = 0; mt < 2; ++mt)                                    \
                areg[(r + 2) % 3][mt] =                                       \
                    *(const bf16x8*)(Aq + (size_t)(kt_ + 2) * 512 + mt * 16); \
        }                                                                     \
        if (r == 1 && cc_ < 15) {                                             \
            const u16* gs = pbase + (cc_ + 1) * 32;                           \
            gl_lds16(gs + src0, &Bt[(CBV) ^ 1][tid * 8]);                     \
            if (do1) gl_lds16(gs + src1, &Bt[(CBV) ^ 1][c1 * 8]);             \
        }                                                                     \
        if (r < 7) READB2(breg[(r + 2) % 3], btc, r + 2);                     \
        _Pragma("unroll")                                                     \
        for (int mt = 0; mt < 2; ++mt)                                        \
            _Pragma("unroll")                                                 \
            for (int nt = 0; nt < 2; ++nt)                                    \
                acc[mt][nt] = __builtin_amdgcn_mfma_f32_16x16x32_bf16(        \
                    areg[r % 3][mt], breg[r % 3][nt], acc[mt][nt], 0, 0, 0);  \
    }                                                                         \
}

// ---------------------------------------------------------------------------
// x-part conv GEMM: BM=128, BN=128, waves 4m x 2n, MF=2, NF=4.  N=4096 covers
// 2t x 2b (plane=n>>10: b=plane&1, t=t0+(plane>>1)).  Stores Zx.
// grid (32,16) = 512 blocks -> 2 blocks/CU.
// ---------------------------------------------------------------------------
__global__ __launch_bounds__(512, 4) void conv_gemm(
    const u16* __restrict__ Wp, const u16* __restrict__ Xp, int t0,
    float* __restrict__ Z) {
    __shared__ __align__(16) u16 Bt[2][6528]; // 25.5 KB chunk dbuf

    const int tid = threadIdx.x;
    const int bid = blockIdx.y * 32 + blockIdx.x;     // 0..511
    const int swz = (bid & 7) * 64 + (bid >> 3);      // XCD co-clustered
    const int co_blk = swz >> 5;                       // 0..15
    const int nblk   = swz & 31;
    const int n0 = nblk * 128;

    const int wave = tid >> 6, lane = tid & 63;
    const int wm = wave >> 1, wn = wave & 1;          // 4m x 2n
    const int q_l = lane >> 4, m_l = lane & 15;

    const int plane = n0 >> 10;
    const int bb_ = plane & 1;
    const int tt  = t0 + (plane >> 1);
    const int pyb = (n0 & 1023) >> 5;
    const u16* pbase = Xp + (size_t)(bb_ * T_STEPS + tt) * PLANE * 512;

    // B staging: 816 16B cells = [pos(6*34)][slot(4)], src slot pre-swizzled
    const int c0 = tid;
    const int p0 = c0 >> 2, sl0 = c0 & 3;
    const int yl0 = p0 / 34, xl0 = p0 - yl0 * 34;
    const int src0 = ((pyb + yl0) * 34 + xl0) * 512 + ((sl0 ^ ((xl0 >> 1) & 3)) << 3);
    const int c1 = 512 + tid;
    const int p1 = c1 >> 2, sl1 = c1 & 3;
    const int yl1 = p1 / 34, xl1 = p1 - yl1 * 34;
    const int src1 = ((pyb + yl1) * 34 + xl1) * 512 + ((sl1 ^ ((xl1 >> 1) & 3)) << 3);
    const bool do1 = tid < 304;

    const uint4* Aq = (const uint4*)Wp + (size_t)co_blk * 144 * 512
                      + q_l * 128 + wm * 32 + m_l;

    int colb[2][3];
#pragma unroll
    for (int xh = 0; xh < 2; xh++)
#pragma unroll
        for (int rx = 0; rx < 3; rx++) {
            int xl = xh * 16 + m_l + rx;
            colb[xh][rx] = xl * 64 + ((q_l ^ ((xl >> 1) & 3)) << 4);
        }
    const int wnrow = wn * 2 * ROWB;

    f32x4 acc[2][4];
#pragma unroll
    for (int i = 0; i < 2; i++)
#pragma unroll
        for (int j = 0; j < 4; j++) acc[i][j] = (f32x4){0.f, 0.f, 0.f, 0.f};

    bf16x8 areg[3][2], breg[3][4];

    gl_lds16(pbase + src0, &Bt[0][c0 * 8]);
    if (do1) gl_lds16(pbase + src1, &Bt[0][c1 * 8]);
#pragma unroll
    for (int mt = 0; mt < 2; ++mt) {
        areg[0][mt] = *(const bf16x8*)(Aq + mt * 16);
        areg[1][mt] = *(const bf16x8*)(Aq + 512 + mt * 16);
    }

    XCHUNK(0, 0);
#pragma unroll 1
    for (int cch = 0; cch < 7; ++cch) {
        XCHUNK(2 * cch + 1, 1);
        XCHUNK(2 * cch + 2, 0);
    }
    XCHUNK(15, 1);

#pragma unroll
    for (int mt = 0; mt < 2; mt++)
#pragma unroll
        for (int nt = 0; nt < 4; nt++)
#pragma unroll
            for (int reg = 0; reg < 4; reg++) {
                int co = co_blk * 128 + wm * 32 + mt * 16 + q_l * 4 + reg;
                int n  = n0 + wn * 64 + nt * 16 + m_l;
                Z[(size_t)co * 4096 + n] = acc[mt][nt][reg];
            }
}

// ---------------------------------------------------------------------------
// Fused h-conv GEMM + LSTM gates: BN=64 -> grid (32,16) = 512 blocks
// (2 blocks/CU).  BM=128 with gate-in-reg M layout (m = ch_local*4 + gate):
// C/D row = q_l*4 + reg -> ch_local = wm*8 + mt*4 + q_l, gate = reg, so each
// thread's f32x4 holds all 4 gates of one (ch, n) -> cell math in-register.
// Waves 4m x 2n, MF=2, NF=2.  Y written via LDS transpose (full-line stores).
// ---------------------------------------------------------------------------
__global__ __launch_bounds__(512, 4) void hconv_gates(
    const u16* __restrict__ Wp, const u16* __restrict__ Yprev, int tprev,
    const float* __restrict__ zx, int nxoff,
    const float* __restrict__ bias,
    const float* __restrict__ wci, const float* __restrict__ wcf,
    const float* __restrict__ wco,
    float* __restrict__ C, u16* __restrict__ Yp, int t,
    float* __restrict__ outp) {
    __shared__ __align__(16) u16 Bt[2][4352];  // 17 KB chunk dbuf
    __shared__ u16 Hs[32][66];                 // 4.1 KB Y-transpose staging

    const int tid = threadIdx.x;
    const int bid = blockIdx.y * 32 + blockIdx.x;     // 0..511
    const int swz = (bid & 7) * 64 + (bid >> 3);
    const int co_blk = swz >> 5;                       // 0..15 (32-ch group)
    const int nblk   = swz & 31;                       // 0..31
    const int n0 = nblk * 64;

    const int wave = tid >> 6, lane = tid & 63;
    const int wm = wave >> 1, wn = wave & 1;           // 4m x 2n
    const int q_l = lane >> 4, m_l = lane & 15;

    const int b = n0 >> 10;
    const int pyb = (n0 & 1023) >> 5;                  // first output row (even)
    const u16* pbase = Yprev + (size_t)(b * T_STEPS + tprev) * PLANE * 512;

    // B staging: 544 cells (4 rows x 34 x 4 slots)
    const int p0 = tid >> 2, sl0 = tid & 3;
    const int yl0 = p0 / 34, xl0 = p0 - yl0 * 34;
    const int src0 = ((pyb + yl0) * 34 + xl0) * 512 + ((sl0 ^ ((xl0 >> 1) & 3)) << 3);
    const int c1 = 512 + tid;
    const int p1 = c1 >> 2, sl1 = c1 & 3;
    const int yl1 = p1 / 34, xl1 = p1 - yl1 * 34;
    const int src1 = ((pyb + yl1) * 34 + xl1) * 512 + ((sl1 ^ ((xl1 >> 1) & 3)) << 3);
    const bool do1 = tid < 32;                         // 544 - 512

    const uint4* Aq = (const uint4*)Wp + (size_t)co_blk * 144 * 512
                      + q_l * 128 + wm * 32 + m_l;

    int colb[2][3];
#pragma unroll
    for (int nt = 0; nt < 2; nt++)
#pragma unroll
        for (int rx = 0; rx < 3; rx++) {
            int xl = nt * 16 + m_l + rx;               // 0..33
            colb[nt][rx] = xl * 64 + ((q_l ^ ((xl >> 1) & 3)) << 4);
        }
    const int wnrow = wn * ROWB;                       // wave owns 1 output row

    f32x4 acc[2][2];                                   // [mt][nt], reg = gate
#pragma unroll
    for (int i = 0; i < 2; i++)
#pragma unroll
        for (int j = 0; j < 2; j++) acc[i][j] = (f32x4){0.f, 0.f, 0.f, 0.f};

    bf16x8 areg[3][2], breg[3][2];

    gl_lds16(pbase + src0, &Bt[0][tid * 8]);
    if (do1) gl_lds16(pbase + src1, &Bt[0][c1 * 8]);
#pragma unroll
    for (int mt = 0; mt < 2; ++mt) {
        areg[0][mt] = *(const bf16x8*)(Aq + mt * 16);
        areg[1][mt] = *(const bf16x8*)(Aq + 512 + mt * 16);
    }

    HCHUNK(0, 0);
#pragma unroll 1
    for (int cch = 0; cch < 7; ++cch) {
        HCHUNK(2 * cch + 1, 1);
        HCHUNK(2 * cch + 2, 0);
    }
    HCHUNK(15, 1);

    // ---- fused LSTM cell epilogue: acc[mt][nt][reg] = gate reg of (ch,n) ----
#pragma unroll
    for (int mt = 0; mt < 2; ++mt) {
        const int chl = wm * 8 + mt * 4 + q_l;
        const int ch = co_blk * 32 + chl;
#pragma unroll
        for (int nt = 0; nt < 2; ++nt) {
            const int nloc = wn * 32 + nt * 16 + m_l;
            const int n = n0 + nloc;                  // n = b*1024 + s
            const int s = n & 1023;
            const int zcol = nxoff + n;
            float zi = acc[mt][nt][0] + zx[(size_t)ch * 4096 + zcol]          + bias[ch];
            float zf = acc[mt][nt][1] + zx[(size_t)(512 + ch) * 4096 + zcol]  + bias[512 + ch];
            float zc = acc[mt][nt][2] + zx[(size_t)(1024 + ch) * 4096 + zcol] + bias[1024 + ch];
            float zo = acc[mt][nt][3] + zx[(size_t)(1536 + ch) * 4096 + zcol] + bias[1536 + ch];
            const size_t ci_ = (size_t)(b * 512 + ch) * 1024 + s;
            const int ps = ch * 1024 + s;
            float Cp = C[ci_];
            float gi = sigmoidf(zi + wci[ps] * Cp);
            float gf = sigmoidf(zf + wcf[ps] * Cp);
            float Cn = gf * Cp + gi * fmaxf(zc, 0.f);
            float go = sigmoidf(zo + wco[ps] * Cn);
            float Hn = go * fmaxf(Cn, 0.f);
            C[ci_] = Cn;
            Hs[chl][nloc] = f2bf(Hn);
            if (outp) outp[ci_] = sigmoidf(Hn);
        }
    }
    __syncthreads();
    // transposed Y write: 64B (32ch) contiguous per spatial position
    if (tid < 256) {
        const int nl = tid >> 2, cp = (tid & 3) << 3;
        const int s = (n0 & 1023) + nl;
        u16* yd = Yp + (((size_t)(b * T_STEPS + t) * 34 + (s >> 5) + 1) * 34
                        + (s & 31) + 1) * 512 + co_blk * 32 + cp;
        union { u16 u[8]; uint4 v; } pk;
#pragma unroll
        for (int j = 0; j < 8; ++j) pk.u[j] = Hs[cp + j][nl];
        *(uint4*)yd = pk.v;
    }
}

// ---------------------------------------------------------------------------
// Standalone gates (t=0 only: H_{-1}=C_{-1}=0, no h-GEMM).
// ---------------------------------------------------------------------------
__global__ __launch_bounds__(256) void gates_kernel(
    const float* __restrict__ zx, int nxoff,
    const float* __restrict__ bias,
    const float* __restrict__ wci, const float* __restrict__ wcf,
    const float* __restrict__ wco,
    float* __restrict__ C, int is_first,
    u16* __restrict__ Yp, int t,
    float* __restrict__ outp) {
    __shared__ u16 Hs[16][136];
    const int tid = threadIdx.x;
    const int s0  = blockIdx.x * 128;
    const int co0 = blockIdx.y * 16;
    const int b   = blockIdx.z;
    const int sl = tid & 127, ch = tid >> 7;
    const int s = s0 + sl;

#pragma unroll
    for (int k = 0; k < 8; ++k) {
        const int co = co0 + k * 2 + ch;
        const size_t zi_ = (size_t)co * 4096 + nxoff + b * 1024 + s;
        float zi = zx[zi_]                       + bias[co];
        float zf = zx[zi_ + (size_t)512 * 4096]  + bias[co + 512];
        float zc = zx[zi_ + (size_t)1024 * 4096] + bias[co + 1024];
        float zo = zx[zi_ + (size_t)1536 * 4096] + bias[co + 1536];
        const size_t ci_ = ((size_t)b * 512 + co) * 1024 + s;
        float Cp = is_first ? 0.f : C[ci_];
        const int ps = co * 1024 + s;
        float gi = sigmoidf(zi + wci[ps] * Cp);
        float gf = sigmoidf(zf + wcf[ps] * Cp);
        float Cn = gf * Cp + gi * fmaxf(zc, 0.f);
        float go = sigmoidf(zo + wco[ps] * Cn);
        float Hn = go * fmaxf(Cn, 0.f);
        C[ci_] = Cn;
        Hs[k * 2 + ch][sl] = f2bf(Hn);
        if (outp) outp[ci_] = sigmoidf(Hn);
    }
    __syncthreads();
    const int sl2 = tid & 127, half = tid >> 7;
    const int s2 = s0 + sl2;
    const int yp = (s2 >> 5) + 1, xp = (s2 & 31) + 1;
    u16* dst = Yp + (((size_t)(b * T_STEPS + t) * 34 + yp) * 34 + xp) * 512
                  + co0 + half * 8;
    union { u16 u[8]; uint4 v; } pk;
#pragma unroll
    for (int j = 0; j < 8; ++j) pk.u[j] = Hs[half * 8 + j][sl2];
    *(uint4*)dst = pk.v;
}

// ---------------------------------------------------------------------------
extern "C" void kernel_launch(void* const* d_in, const int* in_sizes, int n_in,
                              void* d_out, int out_size, void* d_ws, size_t ws_size,
                              hipStream_t stream) {
    const float* x = (const float*)d_in[0];

    char* ws = (char*)d_ws;
    size_t off = 0;
    auto carve = [&](size_t bytes) { char* p = ws + off; off += (bytes + 255) & ~(size_t)255; return p; };

    u16*   Wx   = (u16*)  carve((size_t)16 * 144 * 4096 * 2);   // 18.9 MB
    u16*   Wh   = (u16*)  carve((size_t)16 * 144 * 4096 * 2);   // 18.9 MB
    float* Zx   = (float*)carve((size_t)2048 * 4096 * 4);       // 33.6 MB
    float* Cbuf = (float*)carve((size_t)2 * 512 * 1024 * 4);    //  4.2 MB
    const size_t PADB = (size_t)16 * PLANE * 512 * 2;           // 18.9 MB padded Y/X
    u16*   Yp1  = (u16*)  carve(PADB);
    u16*   Yp2  = (u16*)  carve(PADB);                          // doubles as Xp
    (void)ws_size; (void)in_sizes; (void)n_in; (void)out_size;  // ~113 MB total

    hipMemsetAsync(Yp1, 0, PADB, stream);                       // zero borders
    hipMemsetAsync(Yp2, 0, PADB, stream);
    pretransform_x<<<512, 256, 0, stream>>>(x, Yp2);

    for (int l = 0; l < 3; ++l) {
        const float* w    = (const float*)d_in[1 + 5 * l];
        const float* bias = (const float*)d_in[2 + 5 * l];
        const float* wci  = (const float*)d_in[3 + 5 * l];
        const float* wcf  = (const float*)d_in[4 + 5 * l];
        const float* wco  = (const float*)d_in[5 + 5 * l];
        const u16* inl = (l == 0) ? Yp2 : (l == 1 ? Yp1 : Yp2);
        u16* Ycur      = (l == 0) ? Yp1 : (l == 1 ? Yp2 : Yp1);

        repack_w<<<1024, 256, 0, stream>>>(w, Wx, Wh);

        for (int t = 0; t < T_STEPS; ++t) {
            if ((t & 1) == 0)   // x-part for timesteps t, t+1: N = 4096
                conv_gemm<<<dim3(32, 16), 512, 0, stream>>>(Wx, inl, t, Zx);
            float* outp = (l == 2 && t == T_STEPS - 1) ? (float*)d_out : nullptr;
            if (t == 0) {
                gates_kernel<<<dim3(8, 32, 2), 256, 0, stream>>>(
                    Zx, 0, bias, wci, wcf, wco, Cbuf, 1, Ycur, 0, outp);
            } else {
                hconv_gates<<<dim3(32, 16), 512, 0, stream>>>(
                    Wh, Ycur, t - 1, Zx, (t & 1) * 2048,
                    bias, wci, wcf, wco, Cbuf, Ycur, t, outp);
            }
        }
    }
}

// Round 8
// 2050.289 us; speedup vs baseline: 1.0406x; 1.0406x over previous
//
#include <hip/hip_runtime.h>

typedef unsigned short u16;
typedef __bf16 bf16x8 __attribute__((ext_vector_type(8)));
typedef float f32x4 __attribute__((ext_vector_type(4)));

#define T_STEPS 8
#define PLANE 1156            // 34*34 padded spatial positions
#define ROWB 2176             // 34 * 32ch * 2B : bytes per padded row in LDS tile
#define LDZ 6144              // Zx: 3 regions x 2048 cols

__device__ __forceinline__ u16 f2bf(float f) {
    unsigned u = __float_as_uint(f);
    return (u16)((u + 0x7fff + ((u >> 16) & 1)) >> 16);
}
__device__ __forceinline__ float sigmoidf(float x) {
    return 1.f / (1.f + expf(-x));
}
// async global->LDS, 16B per lane. LDS dest must be base + lane*16 (linear).
__device__ __forceinline__ void gl_lds16(const void* g, void* l) {
    __builtin_amdgcn_global_load_lds(
        (const __attribute__((address_space(1))) void*)g,
        (__attribute__((address_space(3))) void*)l, 16, 0, 0);
}

// ---------------------------------------------------------------------------
// Repack conv_w (fp32) [2048][1024][3][3] -> bf16 GEMM layouts, K reordered
// ci-chunk-major: kt = cc*9 + r.  Both: [co_blk(16)][kt(144)][quad(4)]
// [co_in(128)][j(8)].
// x rows: co = co_blk*128 + co_in (plain).
// h rows gate-in-reg: co = (co_in&3)*512 + co_blk*32 + (co_in>>2).
// ---------------------------------------------------------------------------
__global__ __launch_bounds__(256) void repack_w(const float* __restrict__ w,
                         u16* __restrict__ wx, u16* __restrict__ wh) {
    __shared__ u16 L[128][150];               // 144 used; 150 breaks conflicts
    const int tid = threadIdx.x;
    const int bidx = blockIdx.x;              // 1024 blocks
    const int part   = bidx >> 9;             // 0 = x, 1 = h
    const int co_blk = (bidx >> 5) & 15;
    const int cc     = (bidx >> 1) & 15;
    const int half   = bidx & 1;              // quads 2*half .. 2*half+1
    const int cibase = part * 512 + cc * 32 + half * 16;

#pragma unroll
    for (int k = 0; k < 18; ++k) {
        int i = tid + k * 256;                // 0..4607 (128 rows x 36 float4)
        int co_in = i / 36;
        int p4 = i - co_in * 36;
        int co = part ? ((co_in & 3) * 512 + co_blk * 32 + (co_in >> 2))
                      : (co_blk * 128 + co_in);
        const float4 v = *(const float4*)(w + (size_t)co * 9216
                                            + (size_t)cibase * 9 + p4 * 4);
        L[co_in][p4 * 4 + 0] = f2bf(v.x);
        L[co_in][p4 * 4 + 1] = f2bf(v.y);
        L[co_in][p4 * 4 + 2] = f2bf(v.z);
        L[co_in][p4 * 4 + 3] = f2bf(v.w);
    }
    __syncthreads();
    u16* wout = part ? wh : wx;
#pragma unroll
    for (int k = 0; k < 9; ++k) {
        int v2 = tid + k * 256;               // 0..2303
        int co_in = v2 & 127;
        int rq = v2 >> 7;                     // 0..17
        int q01 = rq >= 9;
        int r = rq - q01 * 9;
        int quad = half * 2 + q01;
        union { u16 u[8]; uint4 q; } tmp;
#pragma unroll
        for (int j = 0; j < 8; ++j)
            tmp.u[j] = L[co_in][(q01 * 8 + j) * 9 + r];
        *(uint4*)(wout + ((((size_t)co_blk * 144 + cc * 9 + r) * 4 + quad) * 128
                          + co_in) * 8) = tmp.q;
    }
}

// ---------------------------------------------------------------------------
// x [2][512][8][32][32] f32 -> Xp [b*8+t][34][34][512] bf16 (interior only;
// border pre-zeroed by memset). Reads coalesced along x.
// ---------------------------------------------------------------------------
__global__ __launch_bounds__(256) void pretransform_x(
    const float* __restrict__ x, u16* __restrict__ Xp) {
    const int bt = blockIdx.x >> 5;            // b*8+t
    const int y  = blockIdx.x & 31;
    const int b  = bt >> 3;
    const int xx = threadIdx.x & 31, cg0 = threadIdx.x >> 5;
    const float* src = x + ((size_t)(b * 512) * T_STEPS + (bt & 7)) * 1024
                         + y * 32 + xx;
    u16* dst = Xp + (((size_t)bt * 34 + y + 1) * 34 + (xx + 1)) * 512;
#pragma unroll
    for (int it = 0; it < 8; ++it) {
        const int cig = cg0 + it * 8;          // 0..63 (8-channel group)
        union { u16 u[8]; uint4 v; } pk;
#pragma unroll
        for (int j = 0; j < 8; ++j)
            pk.u[j] = f2bf(src[(size_t)(cig * 8 + j) * 8192]);
        *(uint4*)(dst + cig * 8) = pk.v;
    }
}

#define READB4(dstv, btcp, rr) {                                             \
    const int ry_ = (rr) / 3, rx_ = (rr) % 3;                                \
    dstv[0] = *(const bf16x8*)((btcp) + wnrow + (0 + ry_) * ROWB + colb[0][rx_]); \
    dstv[1] = *(const bf16x8*)((btcp) + wnrow + (0 + ry_) * ROWB + colb[1][rx_]); \
    dstv[2] = *(const bf16x8*)((btcp) + wnrow + (1 + ry_) * ROWB + colb[0][rx_]); \
    dstv[3] = *(const bf16x8*)((btcp) + wnrow + (1 + ry_) * ROWB + colb[1][rx_]); }

#define READB2(dstv, btcp, rr) {                                             \
    const int ry_ = (rr) / 3, rx_ = (rr) % 3;                                \
    dstv[0] = *(const bf16x8*)((btcp) + wnrow + ry_ * ROWB + colb[0][rx_]);  \
    dstv[1] = *(const bf16x8*)((btcp) + wnrow + ry_ * ROWB + colb[1][rx_]); }

// ---------------------------------------------------------------------------
// Combined per-timestep kernel with block-role specialization.
// role = blockIdx.z + role0:
//   role 0: fused h-conv GEMM + LSTM gates (BM=128 gate-in-reg, BN=64,
//           512 blocks, reads Zx region zoffH, writes C / Y / outp).
//   role 1: x-part conv GEMM pair (BM=128, BN=128, N=4096 = 2t x 2b,
//           512 blocks, writes Zx regions zoffA (t0) / zoffB (t0+1)).
// Both roles use the round-6 schedule: A global->VGPR 3-deep ring (+2 taps,
// L2-resident via XCD swizzle), B chunk tile LDS dbuf staged once per 9 taps,
// B frags register-double-buffered, one counted vmcnt + s_barrier per chunk
// (4 prologue / 14 steady), setprio around the MFMA cluster.
// Zx has 3 regions (t mod 3) so in-dispatch hconv(t) reads never alias the
// concurrent x-pair writes (t+1, t+2).
// ---------------------------------------------------------------------------
__global__ __launch_bounds__(512, 4) void lstm_step(
    const u16* __restrict__ Wx, const u16* __restrict__ Wh,
    const u16* __restrict__ Xp, const u16* __restrict__ Yprev,
    int t0x, int zoffA, int zoffB,
    int tprev, int zoffH,
    const float* __restrict__ bias,
    const float* __restrict__ wci, const float* __restrict__ wcf,
    const float* __restrict__ wco,
    float* __restrict__ C, u16* __restrict__ Yp, int t,
    float* __restrict__ outp,
    float* __restrict__ Z, int role0) {
    __shared__ __align__(16) char smem[26112];

    const int tid = threadIdx.x;
    const int wave = tid >> 6, lane = tid & 63;
    const int wm = wave >> 1, wn = wave & 1;          // 4m x 2n
    const int q_l = lane >> 4, m_l = lane & 15;
    const int bid = blockIdx.y * 32 + blockIdx.x;     // 0..511
    const int swz = (bid & 7) * 64 + (bid >> 3);      // XCD co-clustered

    if (blockIdx.z + role0 == 1) {
        // =================== role 1: x-part conv GEMM ===================
        u16 (*Bt)[6528] = (u16(*)[6528])smem;
        const int co_blk = swz >> 5;                   // 0..15
        const int nblk   = swz & 31;
        const int n0 = nblk * 128;

        const int plane = n0 >> 10;
        const int bb_ = plane & 1;
        const int tt  = t0x + (plane >> 1);
        const int pyb = (n0 & 1023) >> 5;
        const u16* pbase = Xp + (size_t)(bb_ * T_STEPS + tt) * PLANE * 512;

        const int c0 = tid;
        const int p0 = c0 >> 2, sl0 = c0 & 3;
        const int yl0 = p0 / 34, xl0 = p0 - yl0 * 34;
        const int src0 = ((pyb + yl0) * 34 + xl0) * 512 + ((sl0 ^ ((xl0 >> 1) & 3)) << 3);
        const int c1 = 512 + tid;
        const int p1 = c1 >> 2, sl1 = c1 & 3;
        const int yl1 = p1 / 34, xl1 = p1 - yl1 * 34;
        const int src1 = ((pyb + yl1) * 34 + xl1) * 512 + ((sl1 ^ ((xl1 >> 1) & 3)) << 3);
        const bool do1 = tid < 304;

        const uint4* Aq = (const uint4*)Wx + (size_t)co_blk * 144 * 512
                          + q_l * 128 + wm * 32 + m_l;

        int colb[2][3];
#pragma unroll
        for (int xh = 0; xh < 2; xh++)
#pragma unroll
            for (int rx = 0; rx < 3; rx++) {
                int xl = xh * 16 + m_l + rx;
                colb[xh][rx] = xl * 64 + ((q_l ^ ((xl >> 1) & 3)) << 4);
            }
        const int wnrow = wn * 2 * ROWB;

        f32x4 acc[2][4];
#pragma unroll
        for (int i = 0; i < 2; i++)
#pragma unroll
            for (int j = 0; j < 4; j++) acc[i][j] = (f32x4){0.f, 0.f, 0.f, 0.f};

        bf16x8 areg[3][2], breg[2][4];

        gl_lds16(pbase + src0, &Bt[0][c0 * 8]);
        if (do1) gl_lds16(pbase + src1, &Bt[0][c1 * 8]);
#pragma unroll
        for (int mt = 0; mt < 2; ++mt) {
            areg[0][mt] = *(const bf16x8*)(Aq + mt * 16);
            areg[1][mt] = *(const bf16x8*)(Aq + 512 + mt * 16);
        }

        for (int cc = 0; cc < 16; ++cc) {
            const int cb = cc & 1;
            const char* btc = (const char*)&Bt[cb][0];
            asm volatile("" ::: "memory");
            if (cc == 0) asm volatile("s_waitcnt vmcnt(4)" ::: "memory");
            else         asm volatile("s_waitcnt vmcnt(14)" ::: "memory");
            __builtin_amdgcn_s_barrier();
            asm volatile("" ::: "memory");
            READB4(breg[0], btc, 0);
#pragma unroll
            for (int r = 0; r < 9; ++r) {
                const int kt = cc * 9 + r;
                if (cc < 15 || r < 7) {
#pragma unroll
                    for (int mt = 0; mt < 2; ++mt)
                        areg[(r + 2) % 3][mt] =
                            *(const bf16x8*)(Aq + (size_t)(kt + 2) * 512 + mt * 16);
                }
                if (r == 1 && cc < 15) {
                    const u16* gs = pbase + (cc + 1) * 32;
                    gl_lds16(gs + src0, &Bt[cb ^ 1][c0 * 8]);
                    if (do1) gl_lds16(gs + src1, &Bt[cb ^ 1][c1 * 8]);
                }
                if (r < 8) READB4(breg[(r + 1) & 1], btc, (r + 1));
                __builtin_amdgcn_s_setprio(1);
#pragma unroll
                for (int mt = 0; mt < 2; ++mt)
#pragma unroll
                    for (int nt = 0; nt < 4; ++nt)
                        acc[mt][nt] = __builtin_amdgcn_mfma_f32_16x16x32_bf16(
                            areg[r % 3][mt], breg[r & 1][nt], acc[mt][nt], 0, 0, 0);
                __builtin_amdgcn_s_setprio(0);
            }
        }

        const int zbase = ((plane >> 1) ? zoffB : zoffA) + (bb_ << 10);
#pragma unroll
        for (int mt = 0; mt < 2; mt++)
#pragma unroll
            for (int nt = 0; nt < 4; nt++)
#pragma unroll
                for (int reg = 0; reg < 4; reg++) {
                    int co = co_blk * 128 + wm * 32 + mt * 16 + q_l * 4 + reg;
                    int nlow = (n0 & 1023) + wn * 64 + nt * 16 + m_l;
                    Z[(size_t)co * LDZ + zbase + nlow] = acc[mt][nt][reg];
                }
    } else {
        // ============ role 0: fused h-conv GEMM + LSTM gates ============
        u16 (*Bt)[4352] = (u16(*)[4352])smem;
        const int co_blk = swz >> 5;                   // 0..15 (32-ch group)
        const int nblk   = swz & 31;                   // 0..31
        const int n0 = nblk * 64;

        const int b = n0 >> 10;
        const int pyb = (n0 & 1023) >> 5;              // first output row (even)
        const u16* pbase = Yprev + (size_t)(b * T_STEPS + tprev) * PLANE * 512;

        const int p0 = tid >> 2, sl0 = tid & 3;
        const int yl0 = p0 / 34, xl0 = p0 - yl0 * 34;
        const int src0 = ((pyb + yl0) * 34 + xl0) * 512 + ((sl0 ^ ((xl0 >> 1) & 3)) << 3);
        const int c1 = 512 + tid;
        const int p1 = c1 >> 2, sl1 = c1 & 3;
        const int yl1 = p1 / 34, xl1 = p1 - yl1 * 34;
        const int src1 = ((pyb + yl1) * 34 + xl1) * 512 + ((sl1 ^ ((xl1 >> 1) & 3)) << 3);
        const bool do1 = tid < 32;                     // 544 - 512

        const uint4* Aq = (const uint4*)Wh + (size_t)co_blk * 144 * 512
                          + q_l * 128 + wm * 32 + m_l;

        int colb[2][3];
#pragma unroll
        for (int nt = 0; nt < 2; nt++)
#pragma unroll
            for (int rx = 0; rx < 3; rx++) {
                int xl = nt * 16 + m_l + rx;           // 0..33
                colb[nt][rx] = xl * 64 + ((q_l ^ ((xl >> 1) & 3)) << 4);
            }
        const int wnrow = wn * ROWB;                   // wave owns 1 output row

        f32x4 acc[2][2];                               // [mt][nt], reg = gate
#pragma unroll
        for (int i = 0; i < 2; i++)
#pragma unroll
            for (int j = 0; j < 2; j++) acc[i][j] = (f32x4){0.f, 0.f, 0.f, 0.f};

        bf16x8 areg[3][2], breg[2][2];

        gl_lds16(pbase + src0, &Bt[0][tid * 8]);
        if (do1) gl_lds16(pbase + src1, &Bt[0][c1 * 8]);
#pragma unroll
        for (int mt = 0; mt < 2; ++mt) {
            areg[0][mt] = *(const bf16x8*)(Aq + mt * 16);
            areg[1][mt] = *(const bf16x8*)(Aq + 512 + mt * 16);
        }

        for (int cc = 0; cc < 16; ++cc) {
            const int cb = cc & 1;
            const char* btc = (const char*)&Bt[cb][0];
            asm volatile("" ::: "memory");
            if (cc == 0) asm volatile("s_waitcnt vmcnt(4)" ::: "memory");
            else         asm volatile("s_waitcnt vmcnt(14)" ::: "memory");
            __builtin_amdgcn_s_barrier();
            asm volatile("" ::: "memory");
            READB2(breg[0], btc, 0);
#pragma unroll
            for (int r = 0; r < 9; ++r) {
                const int kt = cc * 9 + r;
                if (cc < 15 || r < 7) {
#pragma unroll
                    for (int mt = 0; mt < 2; ++mt)
                        areg[(r + 2) % 3][mt] =
                            *(const bf16x8*)(Aq + (size_t)(kt + 2) * 512 + mt * 16);
                }
                if (r == 1 && cc < 15) {
                    const u16* gs = pbase + (cc + 1) * 32;
                    gl_lds16(gs + src0, &Bt[cb ^ 1][tid * 8]);
                    if (do1) gl_lds16(gs + src1, &Bt[cb ^ 1][c1 * 8]);
                }
                if (r < 8) READB2(breg[(r + 1) & 1], btc, (r + 1));
                __builtin_amdgcn_s_setprio(1);
#pragma unroll
                for (int mt = 0; mt < 2; ++mt)
#pragma unroll
                    for (int nt = 0; nt < 2; ++nt)
                        acc[mt][nt] = __builtin_amdgcn_mfma_f32_16x16x32_bf16(
                            areg[r % 3][mt], breg[r & 1][nt], acc[mt][nt], 0, 0, 0);
                __builtin_amdgcn_s_setprio(0);
            }
        }

        // fused LSTM cell epilogue: acc[mt][nt][reg] = gate reg of (ch,n)
#pragma unroll
        for (int mt = 0; mt < 2; ++mt) {
            const int chl = wm * 8 + mt * 4 + q_l;
            const int ch = co_blk * 32 + chl;
#pragma unroll
            for (int nt = 0; nt < 2; ++nt) {
                const int nloc = wn * 32 + nt * 16 + m_l;
                const int n = n0 + nloc;               // n = b*1024 + s
                const int s = n & 1023;
                const int zcol = zoffH + n;
                float zi = acc[mt][nt][0] + Z[(size_t)ch * LDZ + zcol]          + bias[ch];
                float zf = acc[mt][nt][1] + Z[(size_t)(512 + ch) * LDZ + zcol]  + bias[512 + ch];
                float zc = acc[mt][nt][2] + Z[(size_t)(1024 + ch) * LDZ + zcol] + bias[1024 + ch];
                float zo = acc[mt][nt][3] + Z[(size_t)(1536 + ch) * LDZ + zcol] + bias[1536 + ch];
                const size_t ci_ = (size_t)(b * 512 + ch) * 1024 + s;
                const int ps = ch * 1024 + s;
                float Cp = C[ci_];
                float gi = sigmoidf(zi + wci[ps] * Cp);
                float gf = sigmoidf(zf + wcf[ps] * Cp);
                float Cn = gf * Cp + gi * fmaxf(zc, 0.f);
                float go = sigmoidf(zo + wco[ps] * Cn);
                float Hn = go * fmaxf(Cn, 0.f);
                C[ci_] = Cn;
                const int yp = (s >> 5) + 1, xp = (s & 31) + 1;
                Yp[(((size_t)(b * T_STEPS + t) * 34 + yp) * 34 + xp) * 512 + ch] = f2bf(Hn);
                if (outp) outp[ci_] = sigmoidf(Hn);
            }
        }
    }
}

// ---------------------------------------------------------------------------
// Standalone gates (t=0 only: H_{-1}=C_{-1}=0, no h-GEMM).  Reads Zx region 0.
// ---------------------------------------------------------------------------
__global__ __launch_bounds__(256) void gates_kernel(
    const float* __restrict__ zx,
    const float* __restrict__ bias,
    const float* __restrict__ wci, const float* __restrict__ wcf,
    const float* __restrict__ wco,
    float* __restrict__ C,
    u16* __restrict__ Yp, int t,
    float* __restrict__ outp) {
    __shared__ u16 Hs[16][136];
    const int tid = threadIdx.x;
    const int s0  = blockIdx.x * 128;
    const int co0 = blockIdx.y * 16;
    const int b   = blockIdx.z;
    const int sl = tid & 127, ch = tid >> 7;
    const int s = s0 + sl;

#pragma unroll
    for (int k = 0; k < 8; ++k) {
        const int co = co0 + k * 2 + ch;
        const size_t zi_ = (size_t)co * LDZ + b * 1024 + s;
        float zi = zx[zi_]                      + bias[co];
        float zf = zx[zi_ + (size_t)512 * LDZ]  + bias[co + 512];
        float zc = zx[zi_ + (size_t)1024 * LDZ] + bias[co + 1024];
        float zo = zx[zi_ + (size_t)1536 * LDZ] + bias[co + 1536];
        const size_t ci_ = ((size_t)b * 512 + co) * 1024 + s;
        const int ps = co * 1024 + s;
        float gi = sigmoidf(zi);
        float gf = sigmoidf(zf);
        float Cn = gi * fmaxf(zc, 0.f);
        float go = sigmoidf(zo + wco[ps] * Cn);
        float Hn = go * fmaxf(Cn, 0.f);
        (void)gf; (void)wci; (void)wcf;
        C[ci_] = Cn;
        Hs[k * 2 + ch][sl] = f2bf(Hn);
        if (outp) outp[ci_] = sigmoidf(Hn);
    }
    __syncthreads();
    const int sl2 = tid & 127, half = tid >> 7;
    const int s2 = s0 + sl2;
    const int yp = (s2 >> 5) + 1, xp = (s2 & 31) + 1;
    u16* dst = Yp + (((size_t)(b * T_STEPS + t) * 34 + yp) * 34 + xp) * 512
                  + co0 + half * 8;
    union { u16 u[8]; uint4 v; } pk;
#pragma unroll
    for (int j = 0; j < 8; ++j) pk.u[j] = Hs[half * 8 + j][sl2];
    *(uint4*)dst = pk.v;
}

// ---------------------------------------------------------------------------
extern "C" void kernel_launch(void* const* d_in, const int* in_sizes, int n_in,
                              void* d_out, int out_size, void* d_ws, size_t ws_size,
                              hipStream_t stream) {
    const float* x = (const float*)d_in[0];

    char* ws = (char*)d_ws;
    size_t off = 0;
    auto carve = [&](size_t bytes) { char* p = ws + off; off += (bytes + 255) & ~(size_t)255; return p; };

    u16*   Wx   = (u16*)  carve((size_t)16 * 144 * 4096 * 2);   // 18.9 MB
    u16*   Wh   = (u16*)  carve((size_t)16 * 144 * 4096 * 2);   // 18.9 MB
    float* Zx   = (float*)carve((size_t)2048 * LDZ * 4);        // 50.3 MB (3 regions)
    float* Cbuf = (float*)carve((size_t)2 * 512 * 1024 * 4);    //  4.2 MB
    const size_t PADB = (size_t)16 * PLANE * 512 * 2;           // 18.9 MB padded Y/X
    u16*   Yp1  = (u16*)  carve(PADB);
    u16*   Yp2  = (u16*)  carve(PADB);                          // doubles as Xp
    (void)ws_size; (void)in_sizes; (void)n_in; (void)out_size;  // ~130 MB total

    hipMemsetAsync(Yp1, 0, PADB, stream);                       // zero borders
    hipMemsetAsync(Yp2, 0, PADB, stream);
    pretransform_x<<<512, 256, 0, stream>>>(x, Yp2);

    for (int l = 0; l < 3; ++l) {
        const float* w    = (const float*)d_in[1 + 5 * l];
        const float* bias = (const float*)d_in[2 + 5 * l];
        const float* wci  = (const float*)d_in[3 + 5 * l];
        const float* wcf  = (const float*)d_in[4 + 5 * l];
        const float* wco  = (const float*)d_in[5 + 5 * l];
        const u16* inl = (l == 0) ? Yp2 : (l == 1 ? Yp1 : Yp2);
        u16* Ycur      = (l == 0) ? Yp1 : (l == 1 ? Yp2 : Yp1);

        repack_w<<<1024, 256, 0, stream>>>(w, Wx, Wh);

        // t=0: x-pair (0,1) alone (role 1 only), then standalone gates.
        lstm_step<<<dim3(32, 16, 1), 512, 0, stream>>>(
            Wx, Wh, inl, Ycur, /*t0x*/0, /*zoffA*/0, /*zoffB*/2048,
            /*tprev*/0, /*zoffH*/0, bias, wci, wcf, wco,
            Cbuf, Ycur, 0, nullptr, Zx, /*role0*/1);
        gates_kernel<<<dim3(8, 32, 2), 256, 0, stream>>>(
            Zx, bias, wci, wcf, wco, Cbuf, Ycur, 0, nullptr);

        for (int t = 1; t < T_STEPS; ++t) {
            const bool fuse = (t == 1 || t == 3 || t == 5);
            float* outp = (l == 2 && t == T_STEPS - 1) ? (float*)d_out : nullptr;
            const int zoffH = (t % 3) * 2048;
            const int zA = ((t + 1) % 3) * 2048;
            const int zB = ((t + 2) % 3) * 2048;
            lstm_step<<<dim3(32, 16, fuse ? 2 : 1), 512, 0, stream>>>(
                Wx, Wh, inl, Ycur, /*t0x*/t + 1, zA, zB,
                /*tprev*/t - 1, zoffH, bias, wci, wcf, wco,
                Cbuf, Ycur, t, outp, Zx, /*role0*/0);
        }
    }
}